// Round 2
// baseline (621.411 us; speedup 1.0000x reference)
//
#include <hip/hip_runtime.h>
#include <hip/hip_bf16.h>
#include <math.h>

// ---------------------------------------------------------------------------
// ZoomMIL round 5: fused pipeline, 8 dispatches.
//  - GEMMs: double-buffered LDS, ONE barrier per K-step, next-tile global
//    loads issued right after the barrier (latency hides under MFMA)
//  - radix topk + softmax stats fused into last-finishing block of sgemm
//  - split-K h-GEMMs for mid/high (fp32 atomic accumulate, relu deferred)
//  - final pooling split to 32-row blocks; logits in last block
// ---------------------------------------------------------------------------

typedef __attribute__((ext_vector_type(8))) short short8;
typedef __attribute__((ext_vector_type(4))) float float4a;

__device__ __forceinline__ ushort f2bf(float f) {
    unsigned u = __float_as_uint(f);
    return (ushort)((u + 0x7fffu + ((u >> 16) & 1u)) >> 16);
}
__device__ __forceinline__ uint pk2(float a, float b) {
    __hip_bfloat162 t = __float22bfloat162_rn(make_float2(a, b));
    uint u; __builtin_memcpy(&u, &t, 4); return u;
}
__device__ __forceinline__ float aload(const float* p) {
    return __hip_atomic_load(p, __ATOMIC_RELAXED, __HIP_MEMORY_SCOPE_AGENT);
}

// ---------------------------------------------------------------------------
// h-GEMM: C = relu(A[rowmap] @ Bt^T + bias). BM=128,BN=64,BK=32, 4 waves 2x2.
// Double-buffered LDS: 1 barrier per K-step, prefetch next tile after barrier.
// SPLIT=1: blockIdx.z picks K-chunk of 256; atomicAdd fp32 partials, no relu.
// ---------------------------------------------------------------------------
template<int SPLIT>
__global__ __launch_bounds__(256) void zm_hgemm(
    const float* __restrict__ A, int lda,
    const int* __restrict__ rowmap,
    const ushort* __restrict__ Bt,   // [N][K] bf16
    const float* __restrict__ bias,
    float* __restrict__ Cf, ushort* __restrict__ Cb, int ldc, int K)
{
    __shared__ ushort As[2][128 * 40];
    __shared__ ushort Bs[2][64 * 40];
    const int tid = threadIdx.x;
    const int brow = blockIdx.y << 7;
    const int bcol = blockIdx.x << 6;
    const int kbeg = SPLIT ? ((int)blockIdx.z << 8) : 0;
    const int kend = SPLIT ? kbeg + 256 : K;
    const int nsteps = (kend - kbeg) >> 5;

    const int sr = tid >> 1;            // A row 0..127
    const int sk = (tid & 1) << 4;      // A k-half
    int arow = brow + sr;
    if (rowmap) arow = rowmap[arow];
    const float* Ap = A + (size_t)arow * lda;

    const int bn = tid >> 2;            // B n 0..63
    const int bk = (tid & 3) << 3;
    const ushort* Bp = Bt + (size_t)(bcol + bn) * K + bk;

    const int w = tid >> 6;
    const int wm = (w >> 1) << 6;
    const int wn = (w & 1) << 5;
    const int lane = tid & 63;
    const int lm = lane & 15;
    const int lq = lane >> 4;

    float4a acc[4][2] = {};

    // prologue: first tile into registers
    float4 v0, v1, v2, v3; uint4 bld;
    {
        const float* ap = Ap + kbeg + sk;
        v0 = *(const float4*)(ap);
        v1 = *(const float4*)(ap + 4);
        v2 = *(const float4*)(ap + 8);
        v3 = *(const float4*)(ap + 12);
        bld = *(const uint4*)(Bp + kbeg);
    }

    for (int s = 0; s < nsteps; s++) {
        const int cur = s & 1;
        uint4 p0, p1;
        p0.x = pk2(v0.x, v0.y); p0.y = pk2(v0.z, v0.w);
        p0.z = pk2(v1.x, v1.y); p0.w = pk2(v1.z, v1.w);
        p1.x = pk2(v2.x, v2.y); p1.y = pk2(v2.z, v2.w);
        p1.z = pk2(v3.x, v3.y); p1.w = pk2(v3.z, v3.w);
        *(uint4*)&As[cur][sr * 40 + sk]     = p0;
        *(uint4*)&As[cur][sr * 40 + sk + 8] = p1;
        *(uint4*)&Bs[cur][bn * 40 + bk] = bld;
        __syncthreads();
        if (s + 1 < nsteps) {             // prefetch next tile (overlaps MFMA)
            const float* ap = Ap + kbeg + ((s + 1) << 5) + sk;
            v0 = *(const float4*)(ap);
            v1 = *(const float4*)(ap + 4);
            v2 = *(const float4*)(ap + 8);
            v3 = *(const float4*)(ap + 12);
            bld = *(const uint4*)(Bp + kbeg + ((s + 1) << 5));
        }
        short8 afr[4], bfr[2];
#pragma unroll
        for (int mt = 0; mt < 4; mt++)
            afr[mt] = *(const short8*)&As[cur][(wm + mt * 16 + lm) * 40 + lq * 8];
#pragma unroll
        for (int nt = 0; nt < 2; nt++)
            bfr[nt] = *(const short8*)&Bs[cur][(wn + nt * 16 + lm) * 40 + lq * 8];
#pragma unroll
        for (int mt = 0; mt < 4; mt++)
#pragma unroll
            for (int nt = 0; nt < 2; nt++)
                acc[mt][nt] = __builtin_amdgcn_mfma_f32_16x16x32_bf16(
                    afr[mt], bfr[nt], acc[mt][nt], 0, 0, 0);
    }

#pragma unroll
    for (int mt = 0; mt < 4; mt++) {
#pragma unroll
        for (int nt = 0; nt < 2; nt++) {
            int gc = bcol + wn + nt * 16 + lm;
            float bv = bias[gc];
            if (SPLIT && blockIdx.z != 0) bv = 0.0f;
#pragma unroll
            for (int r = 0; r < 4; r++) {
                int gr = brow + wm + mt * 16 + lq * 4 + r;
                float v = acc[mt][nt][r] + bv;
                if (SPLIT) {
                    atomicAdd(&Cf[(size_t)gr * ldc + gc], v);
                } else {
                    v = fmaxf(v, 0.0f);
                    Cf[(size_t)gr * ldc + gc] = v;
                    Cb[(size_t)gr * ldc + gc] = f2bf(v);
                }
            }
        }
    }
}

// ---------------------------------------------------------------------------
// Fused score GEMM: interleaved gating weights (even col=Wa, odd=Wb).
// BM=64,BN=64,BK=32, 4 waves side-by-side, double-buffered LDS (1 barrier).
// Epilogue: tanh/sigmoid pairing via shfl_xor(1), *Wc, lane-reduce, LDS
// wave-combine, atomicAdd to score vec.
// AMODE 0: A bf16; AMODE 1: A fp32 + relu on stage.
// Tail (last finishing block): softmax stats of sMain[0..NS) -> statsOut,
// and if DOTOPK: radix-select top-256 of sAux (ascending-index order, ties
// to lowest index = jax.lax.top_k semantics) -> idx_out + rm_out.
// ---------------------------------------------------------------------------
template<int AMODE, int NS, int DOTOPK>
__global__ __launch_bounds__(256) void zm_sgemm(
    const void* __restrict__ Av, int lda,
    const ushort* __restrict__ Bt,    // [N][512] interleaved bf16
    const float* __restrict__ bint,   // [N] interleaved biases
    const float* __restrict__ wc0, const float* __restrict__ wc1,
    float* __restrict__ sMain, float* __restrict__ sAux,
    const int* __restrict__ idx_prev,
    int* __restrict__ idx_out, int* __restrict__ rm_out,
    float* __restrict__ statsOut, int* __restrict__ cnt2, int lastBlk)
{
    __shared__ ushort As[2][64 * 40];
    __shared__ ushort Bs[2][64 * 40];
    __shared__ float part[4][64];
    const int tid = threadIdx.x;
    const int brow = blockIdx.y << 6;
    const int bcol = blockIdx.x << 6;

    const int sr = tid >> 2;           // 0..63
    const int sk = (tid & 3) << 3;     // 0,8,16,24
    const float*  Af = (const float*)Av;
    const ushort* Ab = (const ushort*)Av;
    const ushort* Bp = Bt + (size_t)(bcol + sr) * 512 + sk;

    const int w = tid >> 6;
    const int wn = w << 4;
    const int lane = tid & 63;
    const int lm = lane & 15;
    const int lq = lane >> 4;

    float4a acc[4] = {};

    uint4 aldu; float4 af0, af1; uint4 bld;
    if (AMODE == 0) {
        aldu = *(const uint4*)(Ab + (size_t)(brow + sr) * lda + sk);
    } else {
        const float* ap = Af + (size_t)(brow + sr) * lda + sk;
        af0 = *(const float4*)ap;
        af1 = *(const float4*)(ap + 4);
    }
    bld = *(const uint4*)(Bp);

    for (int s = 0; s < 16; s++) {
        const int cur = s & 1;
        if (AMODE == 0) {
            *(uint4*)&As[cur][sr * 40 + sk] = aldu;
        } else {
            float4 v0 = af0, v1 = af1;
            v0.x = fmaxf(v0.x, 0.f); v0.y = fmaxf(v0.y, 0.f);
            v0.z = fmaxf(v0.z, 0.f); v0.w = fmaxf(v0.w, 0.f);
            v1.x = fmaxf(v1.x, 0.f); v1.y = fmaxf(v1.y, 0.f);
            v1.z = fmaxf(v1.z, 0.f); v1.w = fmaxf(v1.w, 0.f);
            uint4 pk;
            pk.x = pk2(v0.x, v0.y); pk.y = pk2(v0.z, v0.w);
            pk.z = pk2(v1.x, v1.y); pk.w = pk2(v1.z, v1.w);
            *(uint4*)&As[cur][sr * 40 + sk] = pk;
        }
        *(uint4*)&Bs[cur][sr * 40 + sk] = bld;
        __syncthreads();
        if (s + 1 < 16) {                 // prefetch next tile
            const int k1 = (s + 1) << 5;
            if (AMODE == 0) {
                aldu = *(const uint4*)(Ab + (size_t)(brow + sr) * lda + k1 + sk);
            } else {
                const float* ap = Af + (size_t)(brow + sr) * lda + k1 + sk;
                af0 = *(const float4*)ap;
                af1 = *(const float4*)(ap + 4);
            }
            bld = *(const uint4*)(Bp + k1);
        }
        short8 bfr = *(const short8*)&Bs[cur][(wn + lm) * 40 + lq * 8];
#pragma unroll
        for (int mt = 0; mt < 4; mt++) {
            short8 afr = *(const short8*)&As[cur][(mt * 16 + lm) * 40 + lq * 8];
            acc[mt] = __builtin_amdgcn_mfma_f32_16x16x32_bf16(afr, bfr, acc[mt], 0, 0, 0);
        }
    }

    const int gc = bcol + wn + lm;
    const float* wcp = (gc >= 512) ? wc1 : wc0;
    const float wcv = wcp[(gc & 511) >> 1];
    const float bv = bint[gc];
    const bool odd = (gc & 1);
    float* sp = (bcol >= 512) ? sAux : sMain;

#pragma unroll
    for (int mt = 0; mt < 4; mt++) {
        float red[4];
#pragma unroll
        for (int r = 0; r < 4; r++) {
            float v = acc[mt][r] + bv;
            float x = odd ? (1.0f / (1.0f + expf(-v))) : tanhf(v);
            float prt = __shfl_xor(x, 1);
            float ctr = odd ? 0.0f : (x * prt * wcv);
            ctr += __shfl_xor(ctr, 1);
            ctr += __shfl_xor(ctr, 2);
            ctr += __shfl_xor(ctr, 4);
            ctr += __shfl_xor(ctr, 8);
            red[r] = ctr;
        }
        if (lm == 0) {
#pragma unroll
            for (int r = 0; r < 4; r++) part[w][mt * 16 + lq * 4 + r] = red[r];
        }
    }
    __syncthreads();
    if (tid < 64) {
        float tot = part[0][tid] + part[1][tid] + part[2][tid] + part[3][tid];
        atomicAdd(&sp[brow + tid], tot);
    }

    // ---- fused tail: softmax stats (+ optional radix top-256) ----
    __threadfence();
    __shared__ int lastf;
    if (tid == 0)
        lastf = (__hip_atomic_fetch_add(cnt2, 1, __ATOMIC_ACQ_REL,
                                        __HIP_MEMORY_SCOPE_AGENT) == lastBlk);
    __syncthreads();
    if (!lastf) return;

    {   // softmax stats over sMain[0..NS)
        constexpr int SEPT = NS / 256;
        float* redf = &part[0][0];
        float vv[SEPT];
        float mx = -3.4e38f;
#pragma unroll
        for (int j = 0; j < SEPT; j++) {
            vv[j] = aload(&sMain[tid + j * 256]);
            mx = fmaxf(mx, vv[j]);
        }
        redf[tid] = mx; __syncthreads();
        for (int o = 128; o > 0; o >>= 1) {
            if (tid < o) redf[tid] = fmaxf(redf[tid], redf[tid + o]);
            __syncthreads();
        }
        mx = redf[0]; __syncthreads();
        float z = 0.0f;
#pragma unroll
        for (int j = 0; j < SEPT; j++) z += expf(vv[j] - mx);
        redf[tid] = z; __syncthreads();
        for (int o = 128; o > 0; o >>= 1) {
            if (tid < o) redf[tid] += redf[tid + o];
            __syncthreads();
        }
        if (tid == 0) { statsOut[0] = mx; statsOut[1] = redf[0]; }
    }

    if constexpr (DOTOPK) {
        constexpr int EPT = NS / 256;
        __shared__ int hist[256];
        __shared__ int idxbuf[256];
        __shared__ int wsum[4];
        __shared__ int bcastB, bcastAbove;
        const int w4 = tid >> 6;

        unsigned key[EPT];
#pragma unroll
        for (int e = 0; e < EPT; e++) {
            unsigned u = __float_as_uint(aload(&sAux[tid * EPT + e]));
            key[e] = (u & 0x80000000u) ? ~u : (u | 0x80000000u);
        }
        __syncthreads();

        // 4-pass MSB radix select: T = exact 256th-largest ordered key
        unsigned prefix = 0;
        int remaining = 256;
        for (int pass = 0; pass < 4; pass++) {
            const int shift = 24 - pass * 8;
            hist[tid] = 0;
            __syncthreads();
#pragma unroll
            for (int e = 0; e < EPT; e++) {
                unsigned k = key[e];
                bool ok = (pass == 0) ||
                          ((k >> (shift + 8)) == (prefix >> (shift + 8)));
                if (ok) atomicAdd(&hist[(k >> shift) & 0xff], 1);
            }
            __syncthreads();
            if (tid < 64) {
                int h0 = hist[tid * 4 + 0], h1 = hist[tid * 4 + 1];
                int h2 = hist[tid * 4 + 2], h3 = hist[tid * 4 + 3];
                int q = h0 + h1 + h2 + h3;
                int suf = q;
#pragma unroll
                for (int o = 1; o < 64; o <<= 1) {
                    int v = __shfl_down(suf, o);
                    if (tid + o < 64) suf += v;
                }
                int above = suf - q;
                int c3 = above + h3;
                int c2 = c3 + h2;
                int c1 = c2 + h1;
                int c0 = c1 + h0;
                int cc[4]  = {c0, c1, c2, c3};
                int nxt[4] = {c1, c2, c3, above};
#pragma unroll
                for (int j = 0; j < 4; j++)
                    if (cc[j] >= remaining && nxt[j] < remaining) {
                        bcastB = tid * 4 + j;
                        bcastAbove = nxt[j];
                    }
            }
            __syncthreads();
            prefix |= ((unsigned)bcastB) << shift;
            remaining -= bcastAbove;
            __syncthreads();
        }
        const unsigned T = prefix;
        const int m = remaining;            // #(==T) accepted, >=1

        // stable ascending-index compaction
        int gt = 0, eq = 0;
#pragma unroll
        for (int e = 0; e < EPT; e++) { gt += (key[e] > T); eq += (key[e] == T); }
        int packed = (gt << 16) | eq;
        int incl = packed;
#pragma unroll
        for (int o = 1; o < 64; o <<= 1) {
            int v = __shfl_up(incl, o);
            if (lane >= o) incl += v;
        }
        if (lane == 63) wsum[w4] = incl;
        __syncthreads();
        int wb = 0;
#pragma unroll
        for (int j = 0; j < 4; j++) if (j < w4) wb += wsum[j];
        int base = wb + incl - packed;
        int gt_before = base >> 16;
        int eq_before = base & 0xffff;
#pragma unroll
        for (int e = 0; e < EPT; e++) {
            if (key[e] > T) {
                int eqa = (eq_before < m) ? eq_before : m;
                idxbuf[gt_before + eqa] = tid * EPT + e;
                gt_before++;
            } else if (key[e] == T) {
                if (eq_before < m) idxbuf[gt_before + eq_before] = tid * EPT + e;
                eq_before++;
            }
        }
        __syncthreads();
        idx_out[tid] = idxbuf[tid];
        for (int j = tid; j < 1024; j += 256) {
            int t = idxbuf[j >> 2] * 4 + (j & 3);
            rm_out[j] = idx_prev ? (idx_prev[t >> 4] * 16 + (t & 15)) : t;
        }
    }
}

// ---------------------------------------------------------------------------
// prep: weight transpose-pack (fc + interleaved gating), bias pack, zeroing.
// grid = 1536 (fc tiles) + 1280 (gating tiles) + 1 (bias) + 64 (zero) = 2881
// Vectorized: float4 reads, ushort4 transposed writes.
// ---------------------------------------------------------------------------
__global__ __launch_bounds__(256) void zm_prep(
    const float* __restrict__ fcW,
    const float* __restrict__ gaWa, const float* __restrict__ gaWb,
    const float* __restrict__ gaba, const float* __restrict__ gabb,
    ushort* __restrict__ fc_t, ushort* __restrict__ gint,
    float* __restrict__ bint, float4* __restrict__ zbase, int zn4)
{
    const int b = blockIdx.x;
    const int tid = threadIdx.x;
    if (b >= 2817) {
        float4 z4 = make_float4(0.f, 0.f, 0.f, 0.f);
        for (int i = (b - 2817) * 256 + tid; i < zn4; i += 64 * 256)
            zbase[i] = z4;
        return;
    }
    if (b == 2816) {
        for (int i = tid; i < 2560; i += 256) {
            int n, head;
            if (i < 1024)      { n = i;        head = (n >> 9) ? 3 : 0; }
            else if (i < 2048) { n = i - 1024; head = (n >> 9) ? 4 : 1; }
            else               { n = i - 2048; head = 2; }
            int h = (n & 511) >> 1;
            const float* src = (n & 1) ? gabb : gaba;
            bint[i] = src[head * 256 + h];
        }
        return;
    }
    __shared__ ushort tile[32][33];
    const int r = tid >> 3;             // 0..31
    const int c4 = (tid & 7) << 2;      // 0,4,...,28
    if (b < 1536) {
        int mat = b >> 9, rem = b & 511;
        int tk = rem >> 4, tn = rem & 15;
        const float* src = fcW + (size_t)mat * 1024 * 512;
        ushort* dst = fc_t + (size_t)mat * 512 * 1024;
        int k0 = tk * 32, n0 = tn * 32;
        float4 v = *(const float4*)&src[(size_t)(k0 + r) * 512 + n0 + c4];
        tile[r][c4 + 0] = f2bf(v.x);
        tile[r][c4 + 1] = f2bf(v.y);
        tile[r][c4 + 2] = f2bf(v.z);
        tile[r][c4 + 3] = f2bf(v.w);
        __syncthreads();
        ushort4 o;
        o.x = tile[c4 + 0][r]; o.y = tile[c4 + 1][r];
        o.z = tile[c4 + 2][r]; o.w = tile[c4 + 3][r];
        *(ushort4*)&dst[(size_t)(n0 + r) * 1024 + k0 + c4] = o;
    } else {
        int idx = b - 1536;
        int mat = idx >> 7, rem = idx & 127;
        int tk = rem >> 3, th = rem & 7;
        int head = mat >> 1, br = mat & 1;
        const float* src = (br ? gaWb : gaWa) + (size_t)head * 512 * 256;
        ushort* dstb; int off;
        if (head == 0)      { dstb = gint;              off = 0;   }
        else if (head == 1) { dstb = gint + 1024 * 512; off = 0;   }
        else if (head == 2) { dstb = gint + 2048 * 512; off = 0;   }
        else if (head == 3) { dstb = gint;              off = 512; }
        else                { dstb = gint + 1024 * 512; off = 512; }
        int k0 = tk * 32, h0 = th * 32;
        float4 v = *(const float4*)&src[(size_t)(k0 + r) * 256 + h0 + c4];
        tile[r][c4 + 0] = f2bf(v.x);
        tile[r][c4 + 1] = f2bf(v.y);
        tile[r][c4 + 2] = f2bf(v.z);
        tile[r][c4 + 3] = f2bf(v.w);
        __syncthreads();
        // dst row = interleaved gating col (2*(h0+r)+br); cols = k direction
        ushort4 o;
        o.x = tile[c4 + 0][r]; o.y = tile[c4 + 1][r];
        o.z = tile[c4 + 2][r]; o.w = tile[c4 + 3][r];
        *(ushort4*)&dstb[(size_t)(off + 2 * (h0 + r) + br) * 512 + k0 + c4] = o;
    }
}

// ---------------------------------------------------------------------------
// final: softmax-weighted pooling of all 3 levels into M (atomics), last
// block computes logits. grid = 192 x 256 (32 rows per block).
// ---------------------------------------------------------------------------
__global__ __launch_bounds__(256) void zm_final(
    const float* __restrict__ h1f, const float* __restrict__ h2f,
    const float* __restrict__ h3f,
    const float* __restrict__ s1, const float* __restrict__ s2,
    const float* __restrict__ s3,
    const float* __restrict__ st, float* __restrict__ Mbuf,
    int* __restrict__ cnt,
    const float* __restrict__ Wh, const float* __restrict__ bh,
    float* __restrict__ out)
{
    const int tid = threadIdx.x;
    const int b = blockIdx.x;
    const float* h; const float* s; const float* stp; int r0, rl;
    if (b < 128)      { h = h1f; s = s1; stp = st;     r0 = b * 32;         rl = 0; }
    else if (b < 160) { h = h2f; s = s2; stp = st + 2; r0 = (b - 128) * 32; rl = 1; }
    else              { h = h3f; s = s3; stp = st + 4; r0 = (b - 160) * 32; rl = 1; }
    const float mx = stp[0];
    const float invZ = 1.0f / stp[1];
    float a0 = 0.0f, a1 = 0.0f;
    for (int r = 0; r < 32; r++) {
        int n = r0 + r;
        float wgt = expf(s[n] - mx) * invZ;
        float v0 = h[(size_t)n * 512 + tid];
        float v1 = h[(size_t)n * 512 + 256 + tid];
        if (rl) { v0 = fmaxf(v0, 0.f); v1 = fmaxf(v1, 0.f); }
        a0 += wgt * v0; a1 += wgt * v1;
    }
    atomicAdd(&Mbuf[tid], a0);
    atomicAdd(&Mbuf[tid + 256], a1);
    __threadfence();
    __shared__ int lastf;
    if (tid == 0)
        lastf = (__hip_atomic_fetch_add(cnt, 1, __ATOMIC_ACQ_REL,
                                        __HIP_MEMORY_SCOPE_AGENT) == 191);
    __syncthreads();
    if (lastf) {
        const int c = tid >> 6, lane = tid & 63;
        float pacc = 0.0f;
        for (int f = lane; f < 512; f += 64)
            pacc += aload(&Mbuf[f]) * Wh[f * 4 + c];
        for (int o = 32; o > 0; o >>= 1) pacc += __shfl_down(pacc, o);
        if (lane == 0) out[c] = pacc + bh[c];
    }
}

extern "C" void kernel_launch(void* const* d_in, const int* in_sizes, int n_in,
                              void* d_out, int out_size, void* d_ws, size_t ws_size,
                              hipStream_t stream)
{
    const float* x1   = (const float*)d_in[0];
    const float* x2   = (const float*)d_in[1];
    const float* x3   = (const float*)d_in[2];
    const float* fcW  = (const float*)d_in[3];
    const float* fcb  = (const float*)d_in[4];
    const float* gaWa = (const float*)d_in[5];
    const float* gaba = (const float*)d_in[6];
    const float* gaWb = (const float*)d_in[7];
    const float* gabb = (const float*)d_in[8];
    const float* gaWc = (const float*)d_in[9];
    // gabc (d_in[10]) dropped: softmax/top-k are shift-invariant
    const float* Wh   = (const float*)d_in[11];
    const float* bh   = (const float*)d_in[12];
    float* out = (float*)d_out;

    char* p = (char*)d_ws;
    float*  h1f  = (float*)p;
    ushort* h1b  = (ushort*)(p + 8388608);
    ushort* fc_t = (ushort*)(p + 12582912);
    ushort* gint = (ushort*)(p + 15728640);
    float*  bint = (float*)(p + 18350080);
    float*  st   = (float*)(p + 18360320);
    int*    idx1 = (int*)(p + 18360352);
    int*    idx2 = (int*)(p + 18361376);
    int*    rm2  = (int*)(p + 18362400);
    int*    rm3  = (int*)(p + 18366496);
    char*   zbase = p + 18370592;            // zero region start
    float*  h2f  = (float*)zbase;
    float*  h3f  = (float*)(zbase + 2097152);
    float*  s1   = (float*)(zbase + 4194304);
    float*  s1a  = (float*)(zbase + 4210688);
    float*  s2   = (float*)(zbase + 4227072);
    float*  s2a  = (float*)(zbase + 4231168);
    float*  s3   = (float*)(zbase + 4235264);
    float*  Mbuf = (float*)(zbase + 4239360);
    int*    cnt  = (int*)(zbase + 4241408);  // [0]=final [1]=high [2]=low [3]=mid
    const int ZN4 = 4241424 / 16;

    // 1. prep: pack weights/biases, zero accumulators
    zm_prep<<<2881, 256, 0, stream>>>(fcW, gaWa, gaWb, gaba, gabb,
                                      fc_t, gint, bint, (float4*)zbase, ZN4);
    // 2-3. low mag (sgemm tail: stats s1 + topk s1a -> idx1, rm2)
    zm_hgemm<0><<<dim3(8, 32), 256, 0, stream>>>(x1, 1024, nullptr, fc_t, fcb,
                                                 h1f, h1b, 512, 1024);
    zm_sgemm<0, 4096, 1><<<dim3(16, 64), 256, 0, stream>>>(
        h1b, 512, gint, bint, gaWc, gaWc + 3 * 256,
        s1, s1a, nullptr, idx1, rm2, st, cnt + 2, 1023);
    // 4-5. mid mag (sgemm tail: stats s2 + topk s2a -> idx2, rm3)
    zm_hgemm<1><<<dim3(8, 8, 4), 256, 0, stream>>>(x2, 1024, rm2,
                                                   fc_t + 512 * 1024, fcb + 512,
                                                   h2f, nullptr, 512, 1024);
    zm_sgemm<1, 1024, 1><<<dim3(16, 16), 256, 0, stream>>>(
        h2f, 512, gint + 1024 * 512, bint + 1024, gaWc + 256, gaWc + 4 * 256,
        s2, s2a, idx1, idx2, rm3, st + 2, cnt + 3, 255);
    // 6-7. high mag (sgemm tail: stats s3)
    zm_hgemm<1><<<dim3(8, 8, 4), 256, 0, stream>>>(x3, 1024, rm3,
                                                   fc_t + 2 * 512 * 1024, fcb + 1024,
                                                   h3f, nullptr, 512, 1024);
    zm_sgemm<1, 1024, 0><<<dim3(8, 16), 256, 0, stream>>>(
        h3f, 512, gint + 2048 * 512, bint + 2048, gaWc + 2 * 256, gaWc + 2 * 256,
        s3, s3, nullptr, nullptr, nullptr, st + 4, cnt + 1, 127);
    // 8. pooling + logits
    zm_final<<<192, 256, 0, stream>>>(h1f, h2f, h3f, s1, s2, s3, st, Mbuf, cnt,
                                      Wh, bh, out);
}

// Round 3
// 528.089 us; speedup vs baseline: 1.1767x; 1.1767x over previous
//
#include <hip/hip_runtime.h>
#include <hip/hip_bf16.h>
#include <math.h>

// ---------------------------------------------------------------------------
// ZoomMIL round 6: round-4 (540us) structure + ONE change:
//   hgemm BM 128->64 => 2 blocks/CU (was 1) for memory-level parallelism.
//  - gating GEMM + tanh*sigmoid*Wc fused via interleaved weight packing
//  - split-K h-GEMMs for mid/high (fp32 atomic accumulate, relu deferred)
//  - radix-select topk + stats (separate 2-block kernel, 1024 threads)
//  - wsum+logits fused with device-scope completion counter
// ---------------------------------------------------------------------------

typedef __attribute__((ext_vector_type(8))) short short8;
typedef __attribute__((ext_vector_type(4))) float float4a;

__device__ __forceinline__ ushort f2bf(float f) {
    unsigned u = __float_as_uint(f);
    return (ushort)((u + 0x7fffu + ((u >> 16) & 1u)) >> 16);
}
__device__ __forceinline__ uint pk2(float a, float b) {
    __hip_bfloat162 t = __float22bfloat162_rn(make_float2(a, b));
    uint u; __builtin_memcpy(&u, &t, 4); return u;
}
__device__ __forceinline__ float aload(const float* p) {
    return __hip_atomic_load(p, __ATOMIC_RELAXED, __HIP_MEMORY_SCOPE_AGENT);
}

// ---------------------------------------------------------------------------
// h-GEMM: C = relu(A[rowmap] @ Bt^T + bias). BM=64,BN=64,BK=32, 4 waves 2x2
// (each wave a 32x32 quadrant). 2 blocks/CU for latency hiding.
// SPLIT=1: blockIdx.z picks K-chunk of 256; atomicAdd fp32 partials, no relu.
// ---------------------------------------------------------------------------
template<int SPLIT>
__global__ __launch_bounds__(256) void zm_hgemm(
    const float* __restrict__ A, int lda,
    const int* __restrict__ rowmap,
    const ushort* __restrict__ Bt,   // [N][K] bf16
    const float* __restrict__ bias,
    float* __restrict__ Cf, ushort* __restrict__ Cb, int ldc, int K)
{
    __shared__ ushort As[64 * 40];
    __shared__ ushort Bs[64 * 40];
    const int tid = threadIdx.x;
    const int brow = blockIdx.y << 6;
    const int bcol = blockIdx.x << 6;
    const int kbeg = SPLIT ? ((int)blockIdx.z << 8) : 0;
    const int kend = SPLIT ? kbeg + 256 : K;

    const int sr = tid >> 2;            // A row / B n: 0..63
    const int sk = (tid & 3) << 3;      // k offset 0,8,16,24
    int arow = brow + sr;
    if (rowmap) arow = rowmap[arow];
    const float* Ap = A + (size_t)arow * lda;
    const ushort* Bp = Bt + (size_t)(bcol + sr) * K + sk;

    const int w = tid >> 6;
    const int wm = (w >> 1) << 5;       // 0 or 32
    const int wn = (w & 1) << 5;        // 0 or 32
    const int lane = tid & 63;
    const int lm = lane & 15;
    const int lq = lane >> 4;

    float4a acc[2][2] = {};

    for (int k0 = kbeg; k0 < kend; k0 += 32) {
        const float* ap = Ap + k0 + sk;
        float4 v0 = *(const float4*)(ap);
        float4 v1 = *(const float4*)(ap + 4);
        uint4 p0;
        p0.x = pk2(v0.x, v0.y); p0.y = pk2(v0.z, v0.w);
        p0.z = pk2(v1.x, v1.y); p0.w = pk2(v1.z, v1.w);
        *(uint4*)&As[sr * 40 + sk] = p0;
        *(uint4*)&Bs[sr * 40 + sk] = *(const uint4*)(Bp + k0);
        __syncthreads();
        short8 afr[2], bfr[2];
#pragma unroll
        for (int mt = 0; mt < 2; mt++)
            afr[mt] = *(const short8*)&As[(wm + mt * 16 + lm) * 40 + lq * 8];
#pragma unroll
        for (int nt = 0; nt < 2; nt++)
            bfr[nt] = *(const short8*)&Bs[(wn + nt * 16 + lm) * 40 + lq * 8];
#pragma unroll
        for (int mt = 0; mt < 2; mt++)
#pragma unroll
            for (int nt = 0; nt < 2; nt++)
                acc[mt][nt] = __builtin_amdgcn_mfma_f32_16x16x32_bf16(
                    afr[mt], bfr[nt], acc[mt][nt], 0, 0, 0);
        __syncthreads();
    }

#pragma unroll
    for (int mt = 0; mt < 2; mt++) {
#pragma unroll
        for (int nt = 0; nt < 2; nt++) {
            int gc = bcol + wn + nt * 16 + lm;
            float bv = bias[gc];
            if (SPLIT && blockIdx.z != 0) bv = 0.0f;
#pragma unroll
            for (int r = 0; r < 4; r++) {
                int gr = brow + wm + mt * 16 + lq * 4 + r;
                float v = acc[mt][nt][r] + bv;
                if (SPLIT) {
                    atomicAdd(&Cf[(size_t)gr * ldc + gc], v);
                } else {
                    v = fmaxf(v, 0.0f);
                    Cf[(size_t)gr * ldc + gc] = v;
                    Cb[(size_t)gr * ldc + gc] = f2bf(v);
                }
            }
        }
    }
}

// ---------------------------------------------------------------------------
// Fused score GEMM: interleaved gating weights (even col=Wa, odd=Wb).
// BM=64,BN=64,BK=32, 4 waves side-by-side. Epilogue: tanh/sigmoid pairing via
// shfl_xor(1), *Wc, lane-reduce, LDS wave-combine, atomicAdd to score vec.
// AMODE 0: A bf16; AMODE 1: A fp32 + relu on stage.
// If statsOut != null: last finishing block computes softmax stats of sMain
// (n=1024) -> statsOut[0..1].
// ---------------------------------------------------------------------------
template<int AMODE>
__global__ __launch_bounds__(256) void zm_sgemm(
    const void* __restrict__ Av, int lda,
    const ushort* __restrict__ Bt,    // [N][512] interleaved bf16
    const float* __restrict__ bint,   // [N] interleaved biases
    const float* __restrict__ wc0, const float* __restrict__ wc1,
    float* __restrict__ sMain, float* __restrict__ sAux,
    float* __restrict__ statsOut, int* __restrict__ cnt2, int lastBlk)
{
    __shared__ ushort As[64 * 40];
    __shared__ ushort Bs[64 * 40];
    __shared__ float part[4][64];
    const int tid = threadIdx.x;
    const int brow = blockIdx.y << 6;
    const int bcol = blockIdx.x << 6;

    const int sr = tid >> 2;           // 0..63
    const int sk = (tid & 3) << 3;     // 0,8,16,24
    const float*  Af = (const float*)Av;
    const ushort* Ab = (const ushort*)Av;
    const ushort* Bp = Bt + (size_t)(bcol + sr) * 512 + sk;

    const int w = tid >> 6;
    const int wn = w << 4;
    const int lane = tid & 63;
    const int lm = lane & 15;
    const int lq = lane >> 4;

    float4a acc[4] = {};

    for (int k0 = 0; k0 < 512; k0 += 32) {
        if (AMODE == 0) {
            *(uint4*)&As[sr * 40 + sk] =
                *(const uint4*)(Ab + (size_t)(brow + sr) * lda + k0 + sk);
        } else {
            const float* ap = Af + (size_t)(brow + sr) * lda + k0 + sk;
            float4 v0 = *(const float4*)ap;
            float4 v1 = *(const float4*)(ap + 4);
            v0.x = fmaxf(v0.x, 0.f); v0.y = fmaxf(v0.y, 0.f);
            v0.z = fmaxf(v0.z, 0.f); v0.w = fmaxf(v0.w, 0.f);
            v1.x = fmaxf(v1.x, 0.f); v1.y = fmaxf(v1.y, 0.f);
            v1.z = fmaxf(v1.z, 0.f); v1.w = fmaxf(v1.w, 0.f);
            uint4 pk;
            pk.x = pk2(v0.x, v0.y); pk.y = pk2(v0.z, v0.w);
            pk.z = pk2(v1.x, v1.y); pk.w = pk2(v1.z, v1.w);
            *(uint4*)&As[sr * 40 + sk] = pk;
        }
        *(uint4*)&Bs[sr * 40 + sk] = *(const uint4*)(Bp + k0);
        __syncthreads();
        short8 bfr = *(const short8*)&Bs[(wn + lm) * 40 + lq * 8];
#pragma unroll
        for (int mt = 0; mt < 4; mt++) {
            short8 afr = *(const short8*)&As[(mt * 16 + lm) * 40 + lq * 8];
            acc[mt] = __builtin_amdgcn_mfma_f32_16x16x32_bf16(afr, bfr, acc[mt], 0, 0, 0);
        }
        __syncthreads();
    }

    const int gc = bcol + wn + lm;
    const float* wcp = (gc >= 512) ? wc1 : wc0;
    const float wcv = wcp[(gc & 511) >> 1];
    const float bv = bint[gc];
    const bool odd = (gc & 1);
    float* sp = (bcol >= 512) ? sAux : sMain;

#pragma unroll
    for (int mt = 0; mt < 4; mt++) {
        float red[4];
#pragma unroll
        for (int r = 0; r < 4; r++) {
            float v = acc[mt][r] + bv;
            float x = odd ? (1.0f / (1.0f + expf(-v))) : tanhf(v);
            float prt = __shfl_xor(x, 1);
            float ctr = odd ? 0.0f : (x * prt * wcv);
            ctr += __shfl_xor(ctr, 1);
            ctr += __shfl_xor(ctr, 2);
            ctr += __shfl_xor(ctr, 4);
            ctr += __shfl_xor(ctr, 8);
            red[r] = ctr;
        }
        if (lm == 0) {
#pragma unroll
            for (int r = 0; r < 4; r++) part[w][mt * 16 + lq * 4 + r] = red[r];
        }
    }
    __syncthreads();
    if (tid < 64) {
        float tot = part[0][tid] + part[1][tid] + part[2][tid] + part[3][tid];
        atomicAdd(&sp[brow + tid], tot);
    }

    // optional fused softmax-stats over sMain[0..1023] by last finishing block
    if (statsOut) {
        __threadfence();
        __shared__ int lastf;
        if (tid == 0)
            lastf = (__hip_atomic_fetch_add(cnt2, 1, __ATOMIC_ACQ_REL,
                                            __HIP_MEMORY_SCOPE_AGENT) == lastBlk);
        __syncthreads();
        if (lastf) {
            float* red = (float*)part;   // 256 floats
            float vv[4];
            float mx = -3.4e38f;
#pragma unroll
            for (int j = 0; j < 4; j++) {
                vv[j] = aload(&sMain[tid + j * 256]);
                mx = fmaxf(mx, vv[j]);
            }
            red[tid] = mx; __syncthreads();
            for (int o = 128; o > 0; o >>= 1) {
                if (tid < o) red[tid] = fmaxf(red[tid], red[tid + o]);
                __syncthreads();
            }
            mx = red[0]; __syncthreads();
            float z = 0.0f;
#pragma unroll
            for (int j = 0; j < 4; j++) z += expf(vv[j] - mx);
            red[tid] = z; __syncthreads();
            for (int o = 128; o > 0; o >>= 1) {
                if (tid < o) red[tid] += red[tid + o];
                __syncthreads();
            }
            if (tid == 0) { statsOut[0] = mx; statsOut[1] = red[0]; }
        }
    }
}

// ---------------------------------------------------------------------------
// top-256 (+ rowmap gen) and softmax stats, fused: grid=2 blocks of 1024.
// block0: radix-select threshold (exact 256th-largest ordered key) over
//   sa[0..n), then stable compaction in ascending index order (which is
//   exactly sort(top_k indices)). Ties at threshold take lowest indices —
//   matches jax.lax.top_k tie-breaking.
//   rm_out[j] = t where t = idx[j/4]*4 + j%4, then through idx_prev if given.
// block1: stats of sm -> stOut[0..1].
// ---------------------------------------------------------------------------
__global__ __launch_bounds__(1024) void zm_topk(
    const float* __restrict__ sa, const float* __restrict__ sm, int n,
    const int* __restrict__ idx_prev,
    int* __restrict__ idx_out, int* __restrict__ rm_out,
    float* __restrict__ stOut)
{
    __shared__ float redf[1024];
    __shared__ int hist[256];
    __shared__ int idxbuf[256];
    __shared__ int wsum[16];
    __shared__ int bcastB, bcastAbove;
    const int bs = 1024;
    const int tid = threadIdx.x;

    if (blockIdx.x == 1) {
        float mx = -3.4e38f;
        for (int i = tid; i < n; i += bs) mx = fmaxf(mx, sm[i]);
        redf[tid] = mx; __syncthreads();
        for (int o = 512; o > 0; o >>= 1) {
            if (tid < o) redf[tid] = fmaxf(redf[tid], redf[tid + o]);
            __syncthreads();
        }
        mx = redf[0]; __syncthreads();
        float z = 0.0f;
        for (int i = tid; i < n; i += bs) z += expf(sm[i] - mx);
        redf[tid] = z; __syncthreads();
        for (int o = 512; o > 0; o >>= 1) {
            if (tid < o) redf[tid] += redf[tid + o];
            __syncthreads();
        }
        if (tid == 0) { stOut[0] = mx; stOut[1] = redf[0]; }
        return;
    }

    // ---- block 0: top-256 of sa[0..n) ----
    const int ept = n >> 10;             // elements per thread: 4 (n=4096) or 1
    const int lane = tid & 63;
    unsigned key[4];
#pragma unroll
    for (int e = 0; e < 4; e++) key[e] = 0;
    for (int e = 0; e < ept; e++) {
        unsigned u = __float_as_uint(sa[tid * ept + e]);
        key[e] = (u & 0x80000000u) ? ~u : (u | 0x80000000u);  // order-preserving
    }

    // 4-pass MSB radix select: find exact key T = 256th largest, and
    // m = how many ==T to take (ties by lowest index).
    unsigned prefix = 0;
    int remaining = 256;
    for (int pass = 0; pass < 4; pass++) {
        const int shift = 24 - pass * 8;
        if (tid < 256) hist[tid] = 0;
        __syncthreads();
        for (int e = 0; e < ept; e++) {
            unsigned k = key[e];
            bool ok = (pass == 0) || ((k >> (shift + 8)) == (prefix >> (shift + 8)));
            if (ok) atomicAdd(&hist[(k >> shift) & 0xff], 1);
        }
        __syncthreads();
        if (tid < 64) {
            int h0 = hist[lane * 4 + 0], h1 = hist[lane * 4 + 1];
            int h2 = hist[lane * 4 + 2], h3 = hist[lane * 4 + 3];
            int q = h0 + h1 + h2 + h3;
            int suf = q;                          // inclusive suffix over lanes
#pragma unroll
            for (int o = 1; o < 64; o <<= 1) {
                int v = __shfl_down(suf, o);
                if (lane + o < 64) suf += v;
            }
            int above = suf - q;                  // strictly-above this quad
            int c3 = above + h3;
            int c2 = c3 + h2;
            int c1 = c2 + h1;
            int c0 = c1 + h0;
            int cc[4]  = {c0, c1, c2, c3};
            int nxt[4] = {c1, c2, c3, above};
#pragma unroll
            for (int j = 0; j < 4; j++)
                if (cc[j] >= remaining && nxt[j] < remaining) {
                    bcastB = lane * 4 + j;
                    bcastAbove = nxt[j];
                }
        }
        __syncthreads();
        prefix |= ((unsigned)bcastB) << shift;
        remaining -= bcastAbove;
        __syncthreads();
    }
    const unsigned T = prefix;
    const int m = remaining;                      // #(==T) accepted, >=1

    // stable ascending-index compaction: pos(i) = #gt before + min(#eq before, m)
    int gt = 0, eq = 0;
    for (int e = 0; e < ept; e++) { gt += (key[e] > T); eq += (key[e] == T); }
    int packed = (gt << 16) | eq;
    int incl = packed;
#pragma unroll
    for (int o = 1; o < 64; o <<= 1) {
        int v = __shfl_up(incl, o);
        if (lane >= o) incl += v;
    }
    if (lane == 63) wsum[tid >> 6] = incl;
    __syncthreads();
    if (tid < 64) {
        int v = (tid < 16) ? wsum[tid] : 0;
        int s = v;
#pragma unroll
        for (int o = 1; o < 16; o <<= 1) {
            int t2 = __shfl_up(s, o);
            if (tid >= o) s += t2;
        }
        if (tid < 16) wsum[tid] = s - v;          // exclusive wave base
    }
    __syncthreads();
    int base = wsum[tid >> 6] + incl - packed;    // exclusive prefix (pair)
    int gt_before = base >> 16;
    int eq_before = base & 0xffff;
    for (int e = 0; e < ept; e++) {
        if (key[e] > T) {
            int eqa = (eq_before < m) ? eq_before : m;
            idxbuf[gt_before + eqa] = tid * ept + e;
            gt_before++;
        } else if (key[e] == T) {
            if (eq_before < m) idxbuf[gt_before + eq_before] = tid * ept + e;
            eq_before++;
        }
    }
    __syncthreads();
    if (tid < 256) idx_out[tid] = idxbuf[tid];
    int t = idxbuf[tid >> 2] * 4 + (tid & 3);
    rm_out[tid] = idx_prev ? (idx_prev[t >> 4] * 16 + (t & 15)) : t;
}

// ---------------------------------------------------------------------------
// prep: weight transpose-pack (fc + interleaved gating), bias pack, zeroing.
// grid = 1536 (fc tiles) + 1280 (gating tiles) + 1 (bias) + 64 (zero) = 2881
// ---------------------------------------------------------------------------
__global__ __launch_bounds__(256) void zm_prep(
    const float* __restrict__ fcW,
    const float* __restrict__ gaWa, const float* __restrict__ gaWb,
    const float* __restrict__ gaba, const float* __restrict__ gabb,
    ushort* __restrict__ fc_t, ushort* __restrict__ gint,
    float* __restrict__ bint, float4* __restrict__ zbase, int zn4)
{
    const int b = blockIdx.x;
    const int tid = threadIdx.x;
    if (b >= 2817) {
        float4 z4 = make_float4(0.f, 0.f, 0.f, 0.f);
        for (int i = (b - 2817) * 256 + tid; i < zn4; i += 64 * 256)
            zbase[i] = z4;
        return;
    }
    if (b == 2816) {
        for (int i = tid; i < 2560; i += 256) {
            int n, head;
            if (i < 1024)      { n = i;        head = (n >> 9) ? 3 : 0; }
            else if (i < 2048) { n = i - 1024; head = (n >> 9) ? 4 : 1; }
            else               { n = i - 2048; head = 2; }
            int h = (n & 511) >> 1;
            const float* src = (n & 1) ? gabb : gaba;
            bint[i] = src[head * 256 + h];
        }
        return;
    }
    __shared__ ushort tile[32][33];
    const int c = tid & 31, r8 = tid >> 5;
    if (b < 1536) {
        int mat = b >> 9, rem = b & 511;
        int tk = rem >> 4, tn = rem & 15;
        const float* src = fcW + (size_t)mat * 1024 * 512;
        ushort* dst = fc_t + (size_t)mat * 512 * 1024;
        int k0 = tk * 32, n0 = tn * 32;
#pragma unroll
        for (int it = 0; it < 4; it++) {
            int r = r8 + it * 8;
            tile[r][c] = f2bf(src[(size_t)(k0 + r) * 512 + n0 + c]);
        }
        __syncthreads();
#pragma unroll
        for (int it = 0; it < 4; it++) {
            int r = r8 + it * 8;
            dst[(size_t)(n0 + r) * 1024 + k0 + c] = tile[c][r];
        }
    } else {
        int idx = b - 1536;
        int mat = idx >> 7, rem = idx & 127;
        int tk = rem >> 3, th = rem & 7;
        int head = mat >> 1, br = mat & 1;
        const float* src = (br ? gaWb : gaWa) + (size_t)head * 512 * 256;
        ushort* dstb; int off;
        if (head == 0)      { dstb = gint;              off = 0;   }
        else if (head == 1) { dstb = gint + 1024 * 512; off = 0;   }
        else if (head == 2) { dstb = gint + 2048 * 512; off = 0;   }
        else if (head == 3) { dstb = gint;              off = 512; }
        else                { dstb = gint + 1024 * 512; off = 512; }
        int k0 = tk * 32, h0 = th * 32;
#pragma unroll
        for (int it = 0; it < 4; it++) {
            int r = r8 + it * 8;
            tile[r][c] = f2bf(src[(size_t)(k0 + r) * 256 + h0 + c]);
        }
        __syncthreads();
#pragma unroll
        for (int it = 0; it < 4; it++) {
            int r = r8 + it * 8;  // local h
            dstb[(size_t)(off + 2 * (h0 + r) + br) * 512 + k0 + c] = tile[c][r];
        }
    }
}

// ---------------------------------------------------------------------------
// final: softmax-weighted pooling of all 3 levels into M (atomics), last
// block computes logits. grid = 96 x 256.
// ---------------------------------------------------------------------------
__global__ __launch_bounds__(256) void zm_final(
    const float* __restrict__ h1f, const float* __restrict__ h2f,
    const float* __restrict__ h3f,
    const float* __restrict__ s1, const float* __restrict__ s2,
    const float* __restrict__ s3,
    const float* __restrict__ st, float* __restrict__ Mbuf,
    int* __restrict__ cnt,
    const float* __restrict__ Wh, const float* __restrict__ bh,
    float* __restrict__ out)
{
    const int tid = threadIdx.x;
    const int b = blockIdx.x;
    const float* h; const float* s; const float* stp; int r0, rl;
    if (b < 64)      { h = h1f; s = s1; stp = st;     r0 = b * 64;        rl = 0; }
    else if (b < 80) { h = h2f; s = s2; stp = st + 2; r0 = (b - 64) * 64; rl = 1; }
    else             { h = h3f; s = s3; stp = st + 4; r0 = (b - 80) * 64; rl = 1; }
    const float mx = stp[0];
    const float invZ = 1.0f / stp[1];
    float a0 = 0.0f, a1 = 0.0f;
    for (int r = 0; r < 64; r++) {
        int n = r0 + r;
        float wgt = expf(s[n] - mx) * invZ;
        float v0 = h[(size_t)n * 512 + tid];
        float v1 = h[(size_t)n * 512 + 256 + tid];
        if (rl) { v0 = fmaxf(v0, 0.f); v1 = fmaxf(v1, 0.f); }
        a0 += wgt * v0; a1 += wgt * v1;
    }
    atomicAdd(&Mbuf[tid], a0);
    atomicAdd(&Mbuf[tid + 256], a1);
    __threadfence();
    __shared__ int lastf;
    if (tid == 0)
        lastf = (__hip_atomic_fetch_add(cnt, 1, __ATOMIC_ACQ_REL,
                                        __HIP_MEMORY_SCOPE_AGENT) == 95);
    __syncthreads();
    if (lastf) {
        const int c = tid >> 6, lane = tid & 63;
        float pacc = 0.0f;
        for (int f = lane; f < 512; f += 64)
            pacc += aload(&Mbuf[f]) * Wh[f * 4 + c];
        for (int o = 32; o > 0; o >>= 1) pacc += __shfl_down(pacc, o);
        if (lane == 0) out[c] = pacc + bh[c];
    }
}

extern "C" void kernel_launch(void* const* d_in, const int* in_sizes, int n_in,
                              void* d_out, int out_size, void* d_ws, size_t ws_size,
                              hipStream_t stream)
{
    const float* x1   = (const float*)d_in[0];
    const float* x2   = (const float*)d_in[1];
    const float* x3   = (const float*)d_in[2];
    const float* fcW  = (const float*)d_in[3];
    const float* fcb  = (const float*)d_in[4];
    const float* gaWa = (const float*)d_in[5];
    const float* gaba = (const float*)d_in[6];
    const float* gaWb = (const float*)d_in[7];
    const float* gabb = (const float*)d_in[8];
    const float* gaWc = (const float*)d_in[9];
    // gabc (d_in[10]) dropped: softmax/top-k are shift-invariant
    const float* Wh   = (const float*)d_in[11];
    const float* bh   = (const float*)d_in[12];
    float* out = (float*)d_out;

    char* p = (char*)d_ws;
    float*  h1f  = (float*)p;
    ushort* h1b  = (ushort*)(p + 8388608);
    ushort* fc_t = (ushort*)(p + 12582912);
    ushort* gint = (ushort*)(p + 15728640);
    float*  bint = (float*)(p + 18350080);
    float*  st   = (float*)(p + 18360320);
    int*    idx1 = (int*)(p + 18360352);
    int*    idx2 = (int*)(p + 18361376);
    int*    rm2  = (int*)(p + 18362400);
    int*    rm3  = (int*)(p + 18366496);
    char*   zbase = p + 18370592;            // zero region start
    float*  h2f  = (float*)zbase;
    float*  h3f  = (float*)(zbase + 2097152);
    float*  s1   = (float*)(zbase + 4194304);
    float*  s1a  = (float*)(zbase + 4210688);
    float*  s2   = (float*)(zbase + 4227072);
    float*  s2a  = (float*)(zbase + 4231168);
    float*  s3   = (float*)(zbase + 4235264);
    float*  Mbuf = (float*)(zbase + 4239360);
    int*    cnt  = (int*)(zbase + 4241408);  // [0]=final, [1]=sgemm-high
    const int ZN4 = 4241424 / 16;

    // 1. prep: pack weights/biases, zero accumulators
    zm_prep<<<2881, 256, 0, stream>>>(fcW, gaWa, gaWb, gaba, gabb,
                                      fc_t, gint, bint, (float4*)zbase, ZN4);
    // 2-3. low mag
    zm_hgemm<0><<<dim3(8, 64), 256, 0, stream>>>(x1, 1024, nullptr, fc_t, fcb,
                                                 h1f, h1b, 512, 1024);
    zm_sgemm<0><<<dim3(16, 64), 256, 0, stream>>>(h1b, 512, gint, bint,
                                                  gaWc, gaWc + 3 * 256,
                                                  s1, s1a, nullptr, nullptr, 0);
    // 4. topk low (+stats s1)
    zm_topk<<<2, 1024, 0, stream>>>(s1a, s1, 4096, nullptr, idx1, rm2, st);
    // 5-6. mid mag
    zm_hgemm<1><<<dim3(8, 16, 4), 256, 0, stream>>>(x2, 1024, rm2,
                                                    fc_t + 512 * 1024, fcb + 512,
                                                    h2f, nullptr, 512, 1024);
    zm_sgemm<1><<<dim3(16, 16), 256, 0, stream>>>(h2f, 512, gint + 1024 * 512,
                                                  bint + 1024,
                                                  gaWc + 256, gaWc + 4 * 256,
                                                  s2, s2a, nullptr, nullptr, 0);
    // 7. topk mid (+stats s2)
    zm_topk<<<2, 1024, 0, stream>>>(s2a, s2, 1024, idx1, idx2, rm3, st + 2);
    // 8-9. high mag (sgemm fuses stats s3 via counter)
    zm_hgemm<1><<<dim3(8, 16, 4), 256, 0, stream>>>(x3, 1024, rm3,
                                                    fc_t + 2 * 512 * 1024, fcb + 1024,
                                                    h3f, nullptr, 512, 1024);
    zm_sgemm<1><<<dim3(8, 16), 256, 0, stream>>>(h3f, 512, gint + 2048 * 512,
                                                 bint + 2048,
                                                 gaWc + 2 * 256, gaWc + 2 * 256,
                                                 s3, s3, st + 4, cnt + 1, 127);
    // 10. pooling + logits
    zm_final<<<96, 256, 0, stream>>>(h1f, h2f, h3f, s1, s2, s3, st, Mbuf, cnt,
                                     Wh, bh, out);
}

// Round 4
// 527.006 us; speedup vs baseline: 1.1791x; 1.0021x over previous
//
#include <hip/hip_runtime.h>
#include <hip/hip_bf16.h>
#include <math.h>

// ---------------------------------------------------------------------------
// ZoomMIL round 7: round-6 (528us) structure + two changes:
//  1. topk: adaptive 2048-bin histogram select (1 pass typical, exact) in
//     place of fixed 4-pass radix.
//  2. x1 converted to bf16 once in prep; hgemm-low stages bf16 A directly
//     (halves its A traffic, removes redundant cvt).
// ---------------------------------------------------------------------------

typedef __attribute__((ext_vector_type(8))) short short8;
typedef __attribute__((ext_vector_type(4))) float float4a;

__device__ __forceinline__ ushort f2bf(float f) {
    unsigned u = __float_as_uint(f);
    return (ushort)((u + 0x7fffu + ((u >> 16) & 1u)) >> 16);
}
__device__ __forceinline__ uint pk2(float a, float b) {
    __hip_bfloat162 t = __float22bfloat162_rn(make_float2(a, b));
    uint u; __builtin_memcpy(&u, &t, 4); return u;
}
__device__ __forceinline__ float aload(const float* p) {
    return __hip_atomic_load(p, __ATOMIC_RELAXED, __HIP_MEMORY_SCOPE_AGENT);
}

// ---------------------------------------------------------------------------
// h-GEMM: C = relu(A[rowmap] @ Bt^T + bias). BM=64,BN=64,BK=32, 4 waves 2x2.
// ABF=1: A is bf16 (pre-converted). ABF=0: A fp32, cvt on stage.
// SPLIT=1: blockIdx.z picks K-chunk of 256; atomicAdd fp32 partials, no relu.
// ---------------------------------------------------------------------------
template<int SPLIT, int ABF>
__global__ __launch_bounds__(256) void zm_hgemm(
    const void* __restrict__ Av, int lda,
    const int* __restrict__ rowmap,
    const ushort* __restrict__ Bt,   // [N][K] bf16
    const float* __restrict__ bias,
    float* __restrict__ Cf, ushort* __restrict__ Cb, int ldc, int K)
{
    __shared__ ushort As[64 * 40];
    __shared__ ushort Bs[64 * 40];
    const int tid = threadIdx.x;
    const int brow = blockIdx.y << 6;
    const int bcol = blockIdx.x << 6;
    const int kbeg = SPLIT ? ((int)blockIdx.z << 8) : 0;
    const int kend = SPLIT ? kbeg + 256 : K;

    const int sr = tid >> 2;            // A row / B n: 0..63
    const int sk = (tid & 3) << 3;      // k offset 0,8,16,24
    int arow = brow + sr;
    if (rowmap) arow = rowmap[arow];
    const float*  Apf = (const float*)Av + (size_t)arow * lda;
    const ushort* Apb = (const ushort*)Av + (size_t)arow * lda;
    const ushort* Bp = Bt + (size_t)(bcol + sr) * K + sk;

    const int w = tid >> 6;
    const int wm = (w >> 1) << 5;       // 0 or 32
    const int wn = (w & 1) << 5;        // 0 or 32
    const int lane = tid & 63;
    const int lm = lane & 15;
    const int lq = lane >> 4;

    float4a acc[2][2] = {};

    for (int k0 = kbeg; k0 < kend; k0 += 32) {
        if (ABF) {
            *(uint4*)&As[sr * 40 + sk] = *(const uint4*)(Apb + k0 + sk);
        } else {
            const float* ap = Apf + k0 + sk;
            float4 v0 = *(const float4*)(ap);
            float4 v1 = *(const float4*)(ap + 4);
            uint4 p0;
            p0.x = pk2(v0.x, v0.y); p0.y = pk2(v0.z, v0.w);
            p0.z = pk2(v1.x, v1.y); p0.w = pk2(v1.z, v1.w);
            *(uint4*)&As[sr * 40 + sk] = p0;
        }
        *(uint4*)&Bs[sr * 40 + sk] = *(const uint4*)(Bp + k0);
        __syncthreads();
        short8 afr[2], bfr[2];
#pragma unroll
        for (int mt = 0; mt < 2; mt++)
            afr[mt] = *(const short8*)&As[(wm + mt * 16 + lm) * 40 + lq * 8];
#pragma unroll
        for (int nt = 0; nt < 2; nt++)
            bfr[nt] = *(const short8*)&Bs[(wn + nt * 16 + lm) * 40 + lq * 8];
#pragma unroll
        for (int mt = 0; mt < 2; mt++)
#pragma unroll
            for (int nt = 0; nt < 2; nt++)
                acc[mt][nt] = __builtin_amdgcn_mfma_f32_16x16x32_bf16(
                    afr[mt], bfr[nt], acc[mt][nt], 0, 0, 0);
        __syncthreads();
    }

#pragma unroll
    for (int mt = 0; mt < 2; mt++) {
#pragma unroll
        for (int nt = 0; nt < 2; nt++) {
            int gc = bcol + wn + nt * 16 + lm;
            float bv = bias[gc];
            if (SPLIT && blockIdx.z != 0) bv = 0.0f;
#pragma unroll
            for (int r = 0; r < 4; r++) {
                int gr = brow + wm + mt * 16 + lq * 4 + r;
                float v = acc[mt][nt][r] + bv;
                if (SPLIT) {
                    atomicAdd(&Cf[(size_t)gr * ldc + gc], v);
                } else {
                    v = fmaxf(v, 0.0f);
                    Cf[(size_t)gr * ldc + gc] = v;
                    Cb[(size_t)gr * ldc + gc] = f2bf(v);
                }
            }
        }
    }
}

// ---------------------------------------------------------------------------
// Fused score GEMM: interleaved gating weights (even col=Wa, odd=Wb).
// BM=64,BN=64,BK=32, 4 waves side-by-side. Epilogue: tanh/sigmoid pairing via
// shfl_xor(1), *Wc, lane-reduce, LDS wave-combine, atomicAdd to score vec.
// AMODE 0: A bf16; AMODE 1: A fp32 + relu on stage.
// If statsOut != null: last finishing block computes softmax stats of sMain
// (n=1024) -> statsOut[0..1].
// ---------------------------------------------------------------------------
template<int AMODE>
__global__ __launch_bounds__(256) void zm_sgemm(
    const void* __restrict__ Av, int lda,
    const ushort* __restrict__ Bt,    // [N][512] interleaved bf16
    const float* __restrict__ bint,   // [N] interleaved biases
    const float* __restrict__ wc0, const float* __restrict__ wc1,
    float* __restrict__ sMain, float* __restrict__ sAux,
    float* __restrict__ statsOut, int* __restrict__ cnt2, int lastBlk)
{
    __shared__ ushort As[64 * 40];
    __shared__ ushort Bs[64 * 40];
    __shared__ float part[4][64];
    const int tid = threadIdx.x;
    const int brow = blockIdx.y << 6;
    const int bcol = blockIdx.x << 6;

    const int sr = tid >> 2;           // 0..63
    const int sk = (tid & 3) << 3;     // 0,8,16,24
    const float*  Af = (const float*)Av;
    const ushort* Ab = (const ushort*)Av;
    const ushort* Bp = Bt + (size_t)(bcol + sr) * 512 + sk;

    const int w = tid >> 6;
    const int wn = w << 4;
    const int lane = tid & 63;
    const int lm = lane & 15;
    const int lq = lane >> 4;

    float4a acc[4] = {};

    for (int k0 = 0; k0 < 512; k0 += 32) {
        if (AMODE == 0) {
            *(uint4*)&As[sr * 40 + sk] =
                *(const uint4*)(Ab + (size_t)(brow + sr) * lda + k0 + sk);
        } else {
            const float* ap = Af + (size_t)(brow + sr) * lda + k0 + sk;
            float4 v0 = *(const float4*)ap;
            float4 v1 = *(const float4*)(ap + 4);
            v0.x = fmaxf(v0.x, 0.f); v0.y = fmaxf(v0.y, 0.f);
            v0.z = fmaxf(v0.z, 0.f); v0.w = fmaxf(v0.w, 0.f);
            v1.x = fmaxf(v1.x, 0.f); v1.y = fmaxf(v1.y, 0.f);
            v1.z = fmaxf(v1.z, 0.f); v1.w = fmaxf(v1.w, 0.f);
            uint4 pk;
            pk.x = pk2(v0.x, v0.y); pk.y = pk2(v0.z, v0.w);
            pk.z = pk2(v1.x, v1.y); pk.w = pk2(v1.z, v1.w);
            *(uint4*)&As[sr * 40 + sk] = pk;
        }
        *(uint4*)&Bs[sr * 40 + sk] = *(const uint4*)(Bp + k0);
        __syncthreads();
        short8 bfr = *(const short8*)&Bs[(wn + lm) * 40 + lq * 8];
#pragma unroll
        for (int mt = 0; mt < 4; mt++) {
            short8 afr = *(const short8*)&As[(mt * 16 + lm) * 40 + lq * 8];
            acc[mt] = __builtin_amdgcn_mfma_f32_16x16x32_bf16(afr, bfr, acc[mt], 0, 0, 0);
        }
        __syncthreads();
    }

    const int gc = bcol + wn + lm;
    const float* wcp = (gc >= 512) ? wc1 : wc0;
    const float wcv = wcp[(gc & 511) >> 1];
    const float bv = bint[gc];
    const bool odd = (gc & 1);
    float* sp = (bcol >= 512) ? sAux : sMain;

#pragma unroll
    for (int mt = 0; mt < 4; mt++) {
        float red[4];
#pragma unroll
        for (int r = 0; r < 4; r++) {
            float v = acc[mt][r] + bv;
            float x = odd ? (1.0f / (1.0f + expf(-v))) : tanhf(v);
            float prt = __shfl_xor(x, 1);
            float ctr = odd ? 0.0f : (x * prt * wcv);
            ctr += __shfl_xor(ctr, 1);
            ctr += __shfl_xor(ctr, 2);
            ctr += __shfl_xor(ctr, 4);
            ctr += __shfl_xor(ctr, 8);
            red[r] = ctr;
        }
        if (lm == 0) {
#pragma unroll
            for (int r = 0; r < 4; r++) part[w][mt * 16 + lq * 4 + r] = red[r];
        }
    }
    __syncthreads();
    if (tid < 64) {
        float tot = part[0][tid] + part[1][tid] + part[2][tid] + part[3][tid];
        atomicAdd(&sp[brow + tid], tot);
    }

    // optional fused softmax-stats over sMain[0..1023] by last finishing block
    if (statsOut) {
        __threadfence();
        __shared__ int lastf;
        if (tid == 0)
            lastf = (__hip_atomic_fetch_add(cnt2, 1, __ATOMIC_ACQ_REL,
                                            __HIP_MEMORY_SCOPE_AGENT) == lastBlk);
        __syncthreads();
        if (lastf) {
            float* red = (float*)part;   // 256 floats
            float vv[4];
            float mx = -3.4e38f;
#pragma unroll
            for (int j = 0; j < 4; j++) {
                vv[j] = aload(&sMain[tid + j * 256]);
                mx = fmaxf(mx, vv[j]);
            }
            red[tid] = mx; __syncthreads();
            for (int o = 128; o > 0; o >>= 1) {
                if (tid < o) red[tid] = fmaxf(red[tid], red[tid + o]);
                __syncthreads();
            }
            mx = red[0]; __syncthreads();
            float z = 0.0f;
#pragma unroll
            for (int j = 0; j < 4; j++) z += expf(vv[j] - mx);
            red[tid] = z; __syncthreads();
            for (int o = 128; o > 0; o >>= 1) {
                if (tid < o) red[tid] += red[tid + o];
                __syncthreads();
            }
            if (tid == 0) { statsOut[0] = mx; statsOut[1] = red[0]; }
        }
    }
}

// ---------------------------------------------------------------------------
// top-256 (+ rowmap gen) and softmax stats, fused: grid=2 blocks of 1024.
// block0: adaptive histogram select. Level loop over 11/11/10-bit digits of
//   the order-preserving key: 2048-bin hist -> boundary bin B holding the
//   256th largest; candidates (digit==B) compacted; if <=256 candidates,
//   exact rank-select (full 32-bit keys, ties by lowest index) yields
//   threshold T and accepted-equal count m. Typically 1 level. Then stable
//   ascending-index compaction (= sort(top_k indices), jax tie semantics).
//   rm_out[j] = t where t = idx[j/4]*4 + j%4, then through idx_prev if given.
// block1: stats of sm -> stOut[0..1].
// ---------------------------------------------------------------------------
__global__ __launch_bounds__(1024) void zm_topk(
    const float* __restrict__ sa, const float* __restrict__ sm, int n,
    const int* __restrict__ idx_prev,
    int* __restrict__ idx_out, int* __restrict__ rm_out,
    float* __restrict__ stOut)
{
    __shared__ float redf[1024];
    __shared__ int hist[2048];
    __shared__ unsigned ckey[4096];
    __shared__ int cidx[4096];
    __shared__ int idxbuf[256];
    __shared__ int wsum[16];
    __shared__ int bc[4];           // [0]=B [1]=above [2]=slot [3]=gtT
    __shared__ unsigned bcT;
    const int bs = 1024;
    const int tid = threadIdx.x;

    if (blockIdx.x == 1) {
        float mx = -3.4e38f;
        for (int i = tid; i < n; i += bs) mx = fmaxf(mx, sm[i]);
        redf[tid] = mx; __syncthreads();
        for (int o = 512; o > 0; o >>= 1) {
            if (tid < o) redf[tid] = fmaxf(redf[tid], redf[tid + o]);
            __syncthreads();
        }
        mx = redf[0]; __syncthreads();
        float z = 0.0f;
        for (int i = tid; i < n; i += bs) z += expf(sm[i] - mx);
        redf[tid] = z; __syncthreads();
        for (int o = 512; o > 0; o >>= 1) {
            if (tid < o) redf[tid] += redf[tid + o];
            __syncthreads();
        }
        if (tid == 0) { stOut[0] = mx; stOut[1] = redf[0]; }
        return;
    }

    // ---- block 0: top-256 of sa[0..n) ----
    const int ept = n >> 10;             // 4 (n=4096) or 1 (n=1024)
    const int lane = tid & 63;
    unsigned key[4];
#pragma unroll
    for (int e = 0; e < 4; e++) key[e] = 0;
    for (int e = 0; e < ept; e++) {
        unsigned u = __float_as_uint(sa[tid * ept + e]);
        key[e] = (u & 0x80000000u) ? ~u : (u | 0x80000000u);  // order-preserving
    }

    int need = 256;
    int c = 0;
    for (int level = 0; level < 3; level++) {
        const int shift = (level == 0) ? 21 : ((level == 1) ? 10 : 0);
        hist[tid] = 0; hist[tid + 1024] = 0;
        if (tid == 0) bc[2] = 0;
        __syncthreads();
        if (level == 0) {
            for (int e = 0; e < ept; e++) atomicAdd(&hist[key[e] >> 21], 1);
        } else {
            for (int j = tid; j < c; j += bs)
                atomicAdd(&hist[(ckey[j] >> shift) & 2047], 1);
        }
        __syncthreads();
        // suffix scan over 2048 bins; thread t owns bins 2t, 2t+1
        int h0 = hist[2 * tid], h1 = hist[2 * tid + 1];
        int q = h0 + h1;
        int suf = q;                       // inclusive suffix within wave
#pragma unroll
        for (int o = 1; o < 64; o <<= 1) {
            int v = __shfl_down(suf, o);
            if (lane + o < 64) suf += v;
        }
        if (lane == 0) wsum[tid >> 6] = suf;   // wave total
        __syncthreads();
        if (tid < 16) {
            int v = wsum[tid];
            int s = v;
#pragma unroll
            for (int o = 1; o < 16; o <<= 1) {
                int t2 = __shfl_down(s, o);
                if (tid + o < 16) s += t2;
            }
            wsum[tid] = s - v;             // exclusive suffix (waves above)
        }
        __syncthreads();
        int abv1 = wsum[tid >> 6] + (suf - q); // # in bins > 2t+1
        int abv0 = abv1 + h1;                  // # in bins > 2t
        if (abv1 < need && abv1 + h1 >= need) { bc[0] = 2 * tid + 1; bc[1] = abv1; }
        if (abv0 < need && abv0 + h0 >= need) { bc[0] = 2 * tid;     bc[1] = abv0; }
        __syncthreads();
        const int B = bc[0];
        const int above = bc[1];
        // compact candidates (digit == B)
        if (level == 0) {
            for (int e = 0; e < ept; e++)
                if ((int)(key[e] >> 21) == B) {
                    int s2 = atomicAdd(&bc[2], 1);
                    ckey[s2] = key[e]; cidx[s2] = tid * ept + e;
                }
            __syncthreads();
        } else {
            unsigned rk[4]; int ri[4]; int rc = 0;
            for (int j = tid; j < c; j += bs)
                if ((int)((ckey[j] >> shift) & 2047) == B) {
                    rk[rc] = ckey[j]; ri[rc] = cidx[j]; rc++;
                }
            __syncthreads();
            for (int qq = 0; qq < rc; qq++) {
                int s2 = atomicAdd(&bc[2], 1);
                ckey[s2] = rk[qq]; cidx[s2] = ri[qq];
            }
            __syncthreads();
        }
        c = bc[2];
        need -= above;
        if (c <= 256 || level == 2) break;
    }

    // exact rank-select among c candidates: T = key of rank need-1
    if (tid == 0) bc[3] = 0;
    __syncthreads();
    for (int j = tid; j < c; j += bs) {
        unsigned kj = ckey[j]; int ij = cidx[j];
        int rank = 0;
        for (int i = 0; i < c; i++) {
            unsigned ki = ckey[i];
            rank += (ki > kj) || (ki == kj && cidx[i] < ij);
        }
        if (rank == need - 1) bcT = kj;
    }
    __syncthreads();
    const unsigned T = bcT;
    for (int j = tid; j < c; j += bs)
        if (ckey[j] > T) atomicAdd(&bc[3], 1);
    __syncthreads();
    const int m = need - bc[3];          // accepted ==T count, >=1

    // stable ascending-index compaction: pos(i) = #gt before + min(#eq before, m)
    int gt = 0, eq = 0;
    for (int e = 0; e < ept; e++) { gt += (key[e] > T); eq += (key[e] == T); }
    int packed = (gt << 16) | eq;
    int incl = packed;
#pragma unroll
    for (int o = 1; o < 64; o <<= 1) {
        int v = __shfl_up(incl, o);
        if (lane >= o) incl += v;
    }
    if (lane == 63) wsum[tid >> 6] = incl;
    __syncthreads();
    if (tid < 64) {
        int v = (tid < 16) ? wsum[tid] : 0;
        int s = v;
#pragma unroll
        for (int o = 1; o < 16; o <<= 1) {
            int t2 = __shfl_up(s, o);
            if (tid >= o) s += t2;
        }
        if (tid < 16) wsum[tid] = s - v;          // exclusive wave base
    }
    __syncthreads();
    int base = wsum[tid >> 6] + incl - packed;    // exclusive prefix (pair)
    int gt_before = base >> 16;
    int eq_before = base & 0xffff;
    for (int e = 0; e < ept; e++) {
        if (key[e] > T) {
            int eqa = (eq_before < m) ? eq_before : m;
            idxbuf[gt_before + eqa] = tid * ept + e;
            gt_before++;
        } else if (key[e] == T) {
            if (eq_before < m) idxbuf[gt_before + eq_before] = tid * ept + e;
            eq_before++;
        }
    }
    __syncthreads();
    if (tid < 256) idx_out[tid] = idxbuf[tid];
    int t = idxbuf[tid >> 2] * 4 + (tid & 3);
    rm_out[tid] = idx_prev ? (idx_prev[t >> 4] * 16 + (t & 15)) : t;
}

// ---------------------------------------------------------------------------
// prep: weight transpose-pack (fc + interleaved gating), bias pack, zeroing,
// x1 -> bf16 conversion.
// grid = 1536 (fc) + 1280 (gating) + 1 (bias) + 64 (zero) + 256 (x1cvt) = 3137
// ---------------------------------------------------------------------------
__global__ __launch_bounds__(256) void zm_prep(
    const float* __restrict__ fcW,
    const float* __restrict__ gaWa, const float* __restrict__ gaWb,
    const float* __restrict__ gaba, const float* __restrict__ gabb,
    ushort* __restrict__ fc_t, ushort* __restrict__ gint,
    float* __restrict__ bint, float4* __restrict__ zbase, int zn4,
    const float* __restrict__ x1, ushort* __restrict__ x1b)
{
    const int b = blockIdx.x;
    const int tid = threadIdx.x;
    if (b >= 2881) {                     // x1 fp32 -> bf16 (4096x1024)
        const int base = ((b - 2881) * 256 + tid) * 8;
        for (int it = 0; it < 8; it++) {
            int i = base + it * 524288;  // 65536 threads * 8 elems
            float4 a = *(const float4*)(x1 + i);
            float4 b4 = *(const float4*)(x1 + i + 4);
            uint4 o;
            o.x = pk2(a.x, a.y); o.y = pk2(a.z, a.w);
            o.z = pk2(b4.x, b4.y); o.w = pk2(b4.z, b4.w);
            *(uint4*)(x1b + i) = o;
        }
        return;
    }
    if (b >= 2817) {
        float4 z4 = make_float4(0.f, 0.f, 0.f, 0.f);
        for (int i = (b - 2817) * 256 + tid; i < zn4; i += 64 * 256)
            zbase[i] = z4;
        return;
    }
    if (b == 2816) {
        for (int i = tid; i < 2560; i += 256) {
            int n, head;
            if (i < 1024)      { n = i;        head = (n >> 9) ? 3 : 0; }
            else if (i < 2048) { n = i - 1024; head = (n >> 9) ? 4 : 1; }
            else               { n = i - 2048; head = 2; }
            int h = (n & 511) >> 1;
            const float* src = (n & 1) ? gabb : gaba;
            bint[i] = src[head * 256 + h];
        }
        return;
    }
    __shared__ ushort tile[32][33];
    const int c = tid & 31, r8 = tid >> 5;
    if (b < 1536) {
        int mat = b >> 9, rem = b & 511;
        int tk = rem >> 4, tn = rem & 15;
        const float* src = fcW + (size_t)mat * 1024 * 512;
        ushort* dst = fc_t + (size_t)mat * 512 * 1024;
        int k0 = tk * 32, n0 = tn * 32;
#pragma unroll
        for (int it = 0; it < 4; it++) {
            int r = r8 + it * 8;
            tile[r][c] = f2bf(src[(size_t)(k0 + r) * 512 + n0 + c]);
        }
        __syncthreads();
#pragma unroll
        for (int it = 0; it < 4; it++) {
            int r = r8 + it * 8;
            dst[(size_t)(n0 + r) * 1024 + k0 + c] = tile[c][r];
        }
    } else {
        int idx = b - 1536;
        int mat = idx >> 7, rem = idx & 127;
        int tk = rem >> 3, th = rem & 7;
        int head = mat >> 1, br = mat & 1;
        const float* src = (br ? gaWb : gaWa) + (size_t)head * 512 * 256;
        ushort* dstb; int off;
        if (head == 0)      { dstb = gint;              off = 0;   }
        else if (head == 1) { dstb = gint + 1024 * 512; off = 0;   }
        else if (head == 2) { dstb = gint + 2048 * 512; off = 0;   }
        else if (head == 3) { dstb = gint;              off = 512; }
        else                { dstb = gint + 1024 * 512; off = 512; }
        int k0 = tk * 32, h0 = th * 32;
#pragma unroll
        for (int it = 0; it < 4; it++) {
            int r = r8 + it * 8;
            tile[r][c] = f2bf(src[(size_t)(k0 + r) * 256 + h0 + c]);
        }
        __syncthreads();
#pragma unroll
        for (int it = 0; it < 4; it++) {
            int r = r8 + it * 8;  // local h
            dstb[(size_t)(off + 2 * (h0 + r) + br) * 512 + k0 + c] = tile[c][r];
        }
    }
}

// ---------------------------------------------------------------------------
// final: softmax-weighted pooling of all 3 levels into M (atomics), last
// block computes logits. grid = 96 x 256.
// ---------------------------------------------------------------------------
__global__ __launch_bounds__(256) void zm_final(
    const float* __restrict__ h1f, const float* __restrict__ h2f,
    const float* __restrict__ h3f,
    const float* __restrict__ s1, const float* __restrict__ s2,
    const float* __restrict__ s3,
    const float* __restrict__ st, float* __restrict__ Mbuf,
    int* __restrict__ cnt,
    const float* __restrict__ Wh, const float* __restrict__ bh,
    float* __restrict__ out)
{
    const int tid = threadIdx.x;
    const int b = blockIdx.x;
    const float* h; const float* s; const float* stp; int r0, rl;
    if (b < 64)      { h = h1f; s = s1; stp = st;     r0 = b * 64;        rl = 0; }
    else if (b < 80) { h = h2f; s = s2; stp = st + 2; r0 = (b - 64) * 64; rl = 1; }
    else             { h = h3f; s = s3; stp = st + 4; r0 = (b - 80) * 64; rl = 1; }
    const float mx = stp[0];
    const float invZ = 1.0f / stp[1];
    float a0 = 0.0f, a1 = 0.0f;
    for (int r = 0; r < 64; r++) {
        int n = r0 + r;
        float wgt = expf(s[n] - mx) * invZ;
        float v0 = h[(size_t)n * 512 + tid];
        float v1 = h[(size_t)n * 512 + 256 + tid];
        if (rl) { v0 = fmaxf(v0, 0.f); v1 = fmaxf(v1, 0.f); }
        a0 += wgt * v0; a1 += wgt * v1;
    }
    atomicAdd(&Mbuf[tid], a0);
    atomicAdd(&Mbuf[tid + 256], a1);
    __threadfence();
    __shared__ int lastf;
    if (tid == 0)
        lastf = (__hip_atomic_fetch_add(cnt, 1, __ATOMIC_ACQ_REL,
                                        __HIP_MEMORY_SCOPE_AGENT) == 95);
    __syncthreads();
    if (lastf) {
        const int c = tid >> 6, lane = tid & 63;
        float pacc = 0.0f;
        for (int f = lane; f < 512; f += 64)
            pacc += aload(&Mbuf[f]) * Wh[f * 4 + c];
        for (int o = 32; o > 0; o >>= 1) pacc += __shfl_down(pacc, o);
        if (lane == 0) out[c] = pacc + bh[c];
    }
}

extern "C" void kernel_launch(void* const* d_in, const int* in_sizes, int n_in,
                              void* d_out, int out_size, void* d_ws, size_t ws_size,
                              hipStream_t stream)
{
    const float* x1   = (const float*)d_in[0];
    const float* x2   = (const float*)d_in[1];
    const float* x3   = (const float*)d_in[2];
    const float* fcW  = (const float*)d_in[3];
    const float* fcb  = (const float*)d_in[4];
    const float* gaWa = (const float*)d_in[5];
    const float* gaba = (const float*)d_in[6];
    const float* gaWb = (const float*)d_in[7];
    const float* gabb = (const float*)d_in[8];
    const float* gaWc = (const float*)d_in[9];
    // gabc (d_in[10]) dropped: softmax/top-k are shift-invariant
    const float* Wh   = (const float*)d_in[11];
    const float* bh   = (const float*)d_in[12];
    float* out = (float*)d_out;

    char* p = (char*)d_ws;
    float*  h1f  = (float*)p;
    ushort* h1b  = (ushort*)(p + 8388608);
    ushort* fc_t = (ushort*)(p + 12582912);
    ushort* gint = (ushort*)(p + 15728640);
    float*  bint = (float*)(p + 18350080);
    float*  st   = (float*)(p + 18360320);
    int*    idx1 = (int*)(p + 18360352);
    int*    idx2 = (int*)(p + 18361376);
    int*    rm2  = (int*)(p + 18362400);
    int*    rm3  = (int*)(p + 18366496);
    char*   zbase = p + 18370592;            // zero region start
    float*  h2f  = (float*)zbase;
    float*  h3f  = (float*)(zbase + 2097152);
    float*  s1   = (float*)(zbase + 4194304);
    float*  s1a  = (float*)(zbase + 4210688);
    float*  s2   = (float*)(zbase + 4227072);
    float*  s2a  = (float*)(zbase + 4231168);
    float*  s3   = (float*)(zbase + 4235264);
    float*  Mbuf = (float*)(zbase + 4239360);
    int*    cnt  = (int*)(zbase + 4241408);  // [0]=final, [1]=sgemm-high
    const int ZN4 = 4241424 / 16;
    ushort* x1b  = (ushort*)(p + 22612032);  // 8 MB bf16 copy of x1

    // 1. prep: pack weights/biases, zero accumulators, x1->bf16
    zm_prep<<<3137, 256, 0, stream>>>(fcW, gaWa, gaWb, gaba, gabb,
                                      fc_t, gint, bint, (float4*)zbase, ZN4,
                                      x1, x1b);
    // 2-3. low mag
    zm_hgemm<0, 1><<<dim3(8, 64), 256, 0, stream>>>(x1b, 1024, nullptr, fc_t,
                                                    fcb, h1f, h1b, 512, 1024);
    zm_sgemm<0><<<dim3(16, 64), 256, 0, stream>>>(h1b, 512, gint, bint,
                                                  gaWc, gaWc + 3 * 256,
                                                  s1, s1a, nullptr, nullptr, 0);
    // 4. topk low (+stats s1)
    zm_topk<<<2, 1024, 0, stream>>>(s1a, s1, 4096, nullptr, idx1, rm2, st);
    // 5-6. mid mag
    zm_hgemm<1, 0><<<dim3(8, 16, 4), 256, 0, stream>>>(x2, 1024, rm2,
                                                       fc_t + 512 * 1024,
                                                       fcb + 512,
                                                       h2f, nullptr, 512, 1024);
    zm_sgemm<1><<<dim3(16, 16), 256, 0, stream>>>(h2f, 512, gint + 1024 * 512,
                                                  bint + 1024,
                                                  gaWc + 256, gaWc + 4 * 256,
                                                  s2, s2a, nullptr, nullptr, 0);
    // 7. topk mid (+stats s2)
    zm_topk<<<2, 1024, 0, stream>>>(s2a, s2, 1024, idx1, idx2, rm3, st + 2);
    // 8-9. high mag (sgemm fuses stats s3 via counter)
    zm_hgemm<1, 0><<<dim3(8, 16, 4), 256, 0, stream>>>(x3, 1024, rm3,
                                                       fc_t + 2 * 512 * 1024,
                                                       fcb + 1024,
                                                       h3f, nullptr, 512, 1024);
    zm_sgemm<1><<<dim3(8, 16), 256, 0, stream>>>(h3f, 512, gint + 2048 * 512,
                                                 bint + 2048,
                                                 gaWc + 2 * 256, gaWc + 2 * 256,
                                                 s3, s3, st + 4, cnt + 1, 127);
    // 10. pooling + logits
    zm_final<<<96, 256, 0, stream>>>(h1f, h2f, h3f, s1, s2, s3, st, Mbuf, cnt,
                                     Wh, bh, out);
}